// Round 1
// baseline (154.797 us; speedup 1.0000x reference)
//
#include <hip/hip_runtime.h>
#include <hip/hip_bf16.h>

// VITS length-regulator: attn is one-hot in t per output frame y, so the
// einsums are gathers. Three kernels:
//  1) per-batch ceil(exp(logw))*mask -> inclusive scan -> cum, y_len
//  2) per-(b,y) binary search over cum -> tmap, y_mask
//  3) z_p[b,c,y] = tmap>=0 ? m_p[b,c,t] + noise*exp(logs_p[b,c,t]) : noise

__global__ void k_scan(const float* __restrict__ logw,
                       const int* __restrict__ x_lengths,
                       float* __restrict__ cum,
                       int* __restrict__ y_len,
                       int tx, int max_y) {
    int b = blockIdx.x;
    int t = threadIdx.x;           // blockDim.x == tx (1024)
    __shared__ float s[1024];

    int xl = x_lengths[b];
    if (xl < 1) xl = 1;

    float w = 0.f;
    if (t < tx && t < xl) {
        w = ceilf(expf(logw[b * tx + t]));   // integer-valued float
    }
    s[t] = w;
    __syncthreads();

    // Hillis-Steele inclusive scan (values are integers < 2^24: exact,
    // association order irrelevant -> bit-matches jnp.cumsum)
    for (int off = 1; off < 1024; off <<= 1) {
        float v = 0.f;
        if (t >= off) v = s[t - off];
        __syncthreads();
        if (t >= off) s[t] += v;
        __syncthreads();
    }

    if (t < tx) cum[b * tx + t] = s[t];
    if (t == 0) {
        float tot = s[tx - 1];
        float yl = fminf(fmaxf(tot, 1.f), (float)max_y);
        y_len[b] = (int)yl;
    }
}

__global__ void k_tmap(const float* __restrict__ cum,
                       const int* __restrict__ y_len,
                       int* __restrict__ tmap,
                       float* __restrict__ y_mask_out,
                       int tx, int max_y) {
    int b = blockIdx.y;
    int y = blockIdx.x * blockDim.x + threadIdx.x;
    if (y >= max_y) return;

    int yl = y_len[b];
    int t = -1;
    if (y < yl) {
        // smallest t with cum[t] > y  (strictly increasing within x_len)
        const float* c = cum + b * tx;
        float fy = (float)y;
        int lo = 0, hi = tx - 1;
        while (lo < hi) {
            int mid = (lo + hi) >> 1;
            if (c[mid] > fy) hi = mid; else lo = mid + 1;
        }
        t = lo;
    }
    tmap[b * max_y + y] = t;
    y_mask_out[b * max_y + y] = (y < yl) ? 1.f : 0.f;
}

__global__ void k_expand(const float* __restrict__ m_p,
                         const float* __restrict__ logs_p,
                         const float* __restrict__ noise,
                         const int* __restrict__ tmap,
                         float* __restrict__ z,
                         int C, int tx, int max_y) {
    int b = blockIdx.z;
    int c = blockIdx.y;
    int y = blockIdx.x * blockDim.x + threadIdx.x;
    if (y >= max_y) return;

    int t = tmap[b * max_y + y];
    float n = noise[(size_t)(b * C + c) * max_y + y];
    float out;
    if (t >= 0) {
        size_t idx = (size_t)(b * C + c) * tx + t;
        float m  = m_p[idx];
        float ls = logs_p[idx];
        out = m + n * expf(ls);
    } else {
        out = n;   // m_exp=0, logs_exp=0 -> z = noise*exp(0)
    }
    z[(size_t)(b * C + c) * max_y + y] = out;
}

extern "C" void kernel_launch(void* const* d_in, const int* in_sizes, int n_in,
                              void* d_out, int out_size, void* d_ws, size_t ws_size,
                              hipStream_t stream) {
    const float* m_p    = (const float*)d_in[0];
    const float* logs_p = (const float*)d_in[1];
    const float* logw   = (const float*)d_in[2];
    const float* noise  = (const float*)d_in[3];
    const int*   x_len  = (const int*)  d_in[4];
    // d_in[5] = max_y scalar; shapes are fixed, derive dims from in_sizes.

    const int B    = in_sizes[4];                 // 16
    const int TX   = in_sizes[2] / B;             // 1024
    const int C    = in_sizes[0] / (B * TX);      // 192
    const int MAXY = in_sizes[3] / (B * C);       // 4096

    float* z      = (float*)d_out;                       // [B, C, MAXY]
    float* y_mask = (float*)d_out + (size_t)B * C * MAXY; // [B, 1, MAXY]

    // workspace layout
    float* cum  = (float*)d_ws;                    // B*TX floats
    int*   ylen = (int*)(cum + (size_t)B * TX);    // B ints
    int*   tmap = ylen + ((B + 63) & ~63);         // B*MAXY ints (aligned)

    k_scan<<<dim3(B), dim3(1024), 0, stream>>>(logw, x_len, cum, ylen, TX, MAXY);

    k_tmap<<<dim3((MAXY + 255) / 256, B), dim3(256), 0, stream>>>(
        cum, ylen, tmap, y_mask, TX, MAXY);

    k_expand<<<dim3((MAXY + 255) / 256, C, B), dim3(256), 0, stream>>>(
        m_p, logs_p, noise, tmap, z, C, TX, MAXY);
}

// Round 3
// 130.345 us; speedup vs baseline: 1.1876x; 1.1876x over previous
//
#include <hip/hip_runtime.h>
#include <hip/hip_bf16.h>

// VITS length-regulator: attn is one-hot in t per output frame y, so the
// einsums are gathers. Three kernels:
//  1) per-batch ceil(exp(logw))*mask -> inclusive scan -> cum, y_len
//  2) per-(b,y) binary search over cum -> tmap, y_mask
//  3) per-(b,c) block: stage m row + exp(logs) row in LDS, then
//     z[y] = t>=0 ? m[t] + noise[y]*e[t] : noise[y], vectorized x4.

__global__ void k_scan(const float* __restrict__ logw,
                       const int* __restrict__ x_lengths,
                       float* __restrict__ cum,
                       int* __restrict__ y_len,
                       int tx, int max_y) {
    int b = blockIdx.x;
    int t = threadIdx.x;           // blockDim.x == tx (1024)
    __shared__ float s[1024];

    int xl = x_lengths[b];
    if (xl < 1) xl = 1;

    float w = 0.f;
    if (t < tx && t < xl) {
        w = ceilf(expf(logw[b * tx + t]));   // integer-valued float
    }
    s[t] = w;
    __syncthreads();

    // Hillis-Steele inclusive scan (values are integers < 2^24: exact,
    // association order irrelevant -> bit-matches jnp.cumsum)
    for (int off = 1; off < 1024; off <<= 1) {
        float v = 0.f;
        if (t >= off) v = s[t - off];
        __syncthreads();
        if (t >= off) s[t] += v;
        __syncthreads();
    }

    if (t < tx) cum[b * tx + t] = s[t];
    if (t == 0) {
        float tot = s[tx - 1];
        float yl = fminf(fmaxf(tot, 1.f), (float)max_y);
        y_len[b] = (int)yl;
    }
}

__global__ void k_tmap(const float* __restrict__ cum,
                       const int* __restrict__ y_len,
                       int* __restrict__ tmap,
                       float* __restrict__ y_mask_out,
                       int tx, int max_y) {
    int b = blockIdx.y;
    int y = blockIdx.x * blockDim.x + threadIdx.x;
    if (y >= max_y) return;

    int yl = y_len[b];
    int t = -1;
    if (y < yl) {
        // smallest t with cum[t] > y  (strictly increasing within x_len)
        const float* c = cum + b * tx;
        float fy = (float)y;
        int lo = 0, hi = tx - 1;
        while (lo < hi) {
            int mid = (lo + hi) >> 1;
            if (c[mid] > fy) hi = mid; else lo = mid + 1;
        }
        t = lo;
    }
    tmap[b * max_y + y] = t;
    y_mask_out[b * max_y + y] = (y < yl) ? 1.f : 0.f;
}

// One block per (b,c) row. 256 threads. tx==1024, max_y==4096 assumed
// divisible; dims passed for generality of address math.
__global__ void __launch_bounds__(256) k_expand2(
        const float* __restrict__ m_p,
        const float* __restrict__ logs_p,
        const float* __restrict__ noise,
        const int* __restrict__ tmap,
        float* __restrict__ z,
        int C, int tx, int max_y) {
    __shared__ float sm[1024];   // m_p row
    __shared__ float se[1024];   // exp(logs_p) row

    const int bc  = blockIdx.x;        // b*C + c
    const int b   = bc / C;
    const int tid = threadIdx.x;

    // Stage the row: 256 threads x float4 = 1024 elements each array.
    const float4* m4 = (const float4*)(m_p    + (size_t)bc * tx);
    const float4* l4 = (const float4*)(logs_p + (size_t)bc * tx);
    float4 mv = m4[tid];
    float4 lv = l4[tid];
    int j = tid * 4;
    sm[j + 0] = mv.x; sm[j + 1] = mv.y; sm[j + 2] = mv.z; sm[j + 3] = mv.w;
    se[j + 0] = expf(lv.x); se[j + 1] = expf(lv.y);
    se[j + 2] = expf(lv.z); se[j + 3] = expf(lv.w);
    __syncthreads();

    const float4* n4 = (const float4*)(noise + (size_t)bc * max_y);
    const int4*   t4 = (const int4*)  (tmap  + (size_t)b  * max_y);
    float4*       z4 = (float4*)      (z     + (size_t)bc * max_y);

    const int nvec = max_y >> 2;       // 1024
    for (int i = tid; i < nvec; i += 256) {
        float4 n = n4[i];
        int4   t = t4[i];
        float4 o;
        o.x = (t.x >= 0) ? fmaf(n.x, se[t.x], sm[t.x]) : n.x;
        o.y = (t.y >= 0) ? fmaf(n.y, se[t.y], sm[t.y]) : n.y;
        o.z = (t.z >= 0) ? fmaf(n.z, se[t.z], sm[t.z]) : n.z;
        o.w = (t.w >= 0) ? fmaf(n.w, se[t.w], sm[t.w]) : n.w;
        z4[i] = o;
    }
}

extern "C" void kernel_launch(void* const* d_in, const int* in_sizes, int n_in,
                              void* d_out, int out_size, void* d_ws, size_t ws_size,
                              hipStream_t stream) {
    const float* m_p    = (const float*)d_in[0];
    const float* logs_p = (const float*)d_in[1];
    const float* logw   = (const float*)d_in[2];
    const float* noise  = (const float*)d_in[3];
    const int*   x_len  = (const int*)  d_in[4];

    const int B    = in_sizes[4];                 // 16
    const int TX   = in_sizes[2] / B;             // 1024
    const int C    = in_sizes[0] / (B * TX);      // 192
    const int MAXY = in_sizes[3] / (B * C);       // 4096

    float* z      = (float*)d_out;                        // [B, C, MAXY]
    float* y_mask = (float*)d_out + (size_t)B * C * MAXY; // [B, 1, MAXY]

    // workspace layout
    float* cum  = (float*)d_ws;                    // B*TX floats
    int*   ylen = (int*)(cum + (size_t)B * TX);    // B ints
    int*   tmap = ylen + ((B + 63) & ~63);         // B*MAXY ints (aligned)

    k_scan<<<dim3(B), dim3(1024), 0, stream>>>(logw, x_len, cum, ylen, TX, MAXY);

    k_tmap<<<dim3((MAXY + 255) / 256, B), dim3(256), 0, stream>>>(
        cum, ylen, tmap, y_mask, TX, MAXY);

    k_expand2<<<dim3(B * C), dim3(256), 0, stream>>>(
        m_p, logs_p, noise, tmap, z, C, TX, MAXY);
}

// Round 4
// 127.947 us; speedup vs baseline: 1.2099x; 1.0187x over previous
//
#include <hip/hip_runtime.h>
#include <hip/hip_bf16.h>

// VITS length-regulator: attn is one-hot in t per output frame y, so the
// einsums are gathers. Two kernels:
//  1) k_scan_tmap: per-batch ceil(exp(logw))*mask -> LDS scan -> y_len;
//     binary search per y directly from LDS cum -> tmap (int4) + y_mask.
//  2) k_expand3: per-(b, c0..c0+1) block: stage 2 rows of m + exp(logs) in
//     LDS, 4-deep load pipeline over y, z = t>=0 ? m[t]+noise*e[t] : noise.
//
// Shapes fixed by the problem: B=16, C=192, TX=1024, MAX_Y=4096.

__global__ void __launch_bounds__(1024) k_scan_tmap(
        const float* __restrict__ logw,
        const int* __restrict__ x_lengths,
        int* __restrict__ tmap,
        float* __restrict__ y_mask,
        int tx, int max_y) {
    const int b = blockIdx.x;
    const int t = threadIdx.x;          // blockDim.x == tx == 1024
    __shared__ float s[1024];
    __shared__ int yl_sh;

    int xl = x_lengths[b];
    if (xl < 1) xl = 1;

    float w = 0.f;
    if (t < xl) w = ceilf(expf(logw[b * tx + t]));   // integer-valued float
    s[t] = w;
    __syncthreads();

    // Hillis-Steele inclusive scan (integers < 2^24: exact, order-free)
    for (int off = 1; off < 1024; off <<= 1) {
        float v = 0.f;
        if (t >= off) v = s[t - off];
        __syncthreads();
        if (t >= off) s[t] += v;
        __syncthreads();
    }

    if (t == 0)
        yl_sh = (int)fminf(fmaxf(s[tx - 1], 1.f), (float)max_y);
    __syncthreads();
    const int yl = yl_sh;

    // Each thread handles 4 consecutive y: binary search in LDS cum.
    const int y0 = t * 4;               // max_y/4 == 1024 == blockDim
    int res[4];
    float msk[4];
#pragma unroll
    for (int k = 0; k < 4; ++k) {
        const int y = y0 + k;
        int r = -1;
        if (y < yl) {
            // smallest t with cum[t] > y (cum flat beyond xl, search safe)
            float fy = (float)y;
            int lo = 0, hi = tx - 1;
            while (lo < hi) {
                int mid = (lo + hi) >> 1;
                if (s[mid] > fy) hi = mid; else lo = mid + 1;
            }
            r = lo;
        }
        res[k] = r;
        msk[k] = (y < yl) ? 1.f : 0.f;
    }
    ((int4*)(tmap + (size_t)b * max_y))[t] =
        make_int4(res[0], res[1], res[2], res[3]);
    ((float4*)(y_mask + (size_t)b * max_y))[t] =
        make_float4(msk[0], msk[1], msk[2], msk[3]);
}

// 2 channels per block, 256 threads, 4 y-vec iterations per channel.
// All global loads issued up-front (fully unrolled, static indexing).
__global__ void __launch_bounds__(256) k_expand3(
        const float* __restrict__ m_p,
        const float* __restrict__ logs_p,
        const float* __restrict__ noise,
        const int* __restrict__ tmap,
        float* __restrict__ z,
        int C, int tx, int max_y) {
    __shared__ float sm[2][1024];   // m_p rows
    __shared__ float se[2][1024];   // exp(logs_p) rows

    const int tid   = threadIdx.x;
    const int chunk = blockIdx.x;           // 0 .. B*C/2 - 1
    const int b     = chunk / (C >> 1);
    const int c0    = (chunk - b * (C >> 1)) * 2;
    const size_t row0 = (size_t)b * C + c0;

    // Stage 2 rows of m and exp(logs): 256 threads x float4 each.
#pragma unroll
    for (int r = 0; r < 2; ++r) {
        float4 mv = ((const float4*)(m_p    + (row0 + r) * tx))[tid];
        float4 lv = ((const float4*)(logs_p + (row0 + r) * tx))[tid];
        int j = tid * 4;
        sm[r][j + 0] = mv.x; sm[r][j + 1] = mv.y;
        sm[r][j + 2] = mv.z; sm[r][j + 3] = mv.w;
        se[r][j + 0] = expf(lv.x); se[r][j + 1] = expf(lv.y);
        se[r][j + 2] = expf(lv.z); se[r][j + 3] = expf(lv.w);
    }
    __syncthreads();

    const int4* t4 = (const int4*)(tmap + (size_t)b * max_y);

    // 4 iterations x 2 channels; issue ALL loads first, then gather+store.
    int4   tv[4];
    float4 nv[4][2];
#pragma unroll
    for (int it = 0; it < 4; ++it)
        tv[it] = t4[tid + it * 256];
#pragma unroll
    for (int it = 0; it < 4; ++it) {
        const int i = tid + it * 256;
#pragma unroll
        for (int r = 0; r < 2; ++r)
            nv[it][r] = ((const float4*)(noise + (row0 + r) * max_y))[i];
    }

#pragma unroll
    for (int it = 0; it < 4; ++it) {
        const int i = tid + it * 256;
        const int4 t = tv[it];
#pragma unroll
        for (int r = 0; r < 2; ++r) {
            const float4 n = nv[it][r];
            float4 o;
            o.x = (t.x >= 0) ? fmaf(n.x, se[r][t.x], sm[r][t.x]) : n.x;
            o.y = (t.y >= 0) ? fmaf(n.y, se[r][t.y], sm[r][t.y]) : n.y;
            o.z = (t.z >= 0) ? fmaf(n.z, se[r][t.z], sm[r][t.z]) : n.z;
            o.w = (t.w >= 0) ? fmaf(n.w, se[r][t.w], sm[r][t.w]) : n.w;
            ((float4*)(z + (row0 + r) * max_y))[i] = o;
        }
    }
}

extern "C" void kernel_launch(void* const* d_in, const int* in_sizes, int n_in,
                              void* d_out, int out_size, void* d_ws, size_t ws_size,
                              hipStream_t stream) {
    const float* m_p    = (const float*)d_in[0];
    const float* logs_p = (const float*)d_in[1];
    const float* logw   = (const float*)d_in[2];
    const float* noise  = (const float*)d_in[3];
    const int*   x_len  = (const int*)  d_in[4];

    const int B    = in_sizes[4];                 // 16
    const int TX   = in_sizes[2] / B;             // 1024
    const int C    = in_sizes[0] / (B * TX);      // 192
    const int MAXY = in_sizes[3] / (B * C);       // 4096

    float* z      = (float*)d_out;                        // [B, C, MAXY]
    float* y_mask = (float*)d_out + (size_t)B * C * MAXY; // [B, 1, MAXY]

    int* tmap = (int*)d_ws;                       // B*MAXY ints

    k_scan_tmap<<<dim3(B), dim3(1024), 0, stream>>>(
        logw, x_len, tmap, y_mask, TX, MAXY);

    k_expand3<<<dim3(B * (C >> 1)), dim3(256), 0, stream>>>(
        m_p, logs_p, noise, tmap, z, C, TX, MAXY);
}